// Round 10
// baseline (381.704 us; speedup 1.0000x reference)
//
#include <hip/hip_runtime.h>
#include <math.h>

#define NN 100000
#define NE 1600000
#define BUCKETS ((NN + 255) >> 8)              // 391 buckets of 256 nodes
#define RVPT 4                                  // edges per thread in reorder/bhist

typedef short bf16x8 __attribute__((ext_vector_type(8)));
typedef float f32x4 __attribute__((ext_vector_type(4)));

__device__ inline float bsf(unsigned short u) { return __uint_as_float(((unsigned)u) << 16); }
__device__ inline unsigned short f2bs(float f) {           // RNE, matches np/hw bf16
    unsigned u = __float_as_uint(f);
    return (unsigned short)((u + 0x7fffu + ((u >> 16) & 1u)) >> 16);
}

// ---------------- CSR build (no scattered global atomics) ----------------
__global__ __launch_bounds__(256) void bhist_k(const int* __restrict__ dst,
                                               int* __restrict__ bhist) {
    __shared__ int bh[BUCKETS];
    for (int i = threadIdx.x; i < BUCKETS; i += 256) bh[i] = 0;
    __syncthreads();
    int e0 = blockIdx.x * (256 * RVPT) + threadIdx.x;
#pragma unroll
    for (int v = 0; v < RVPT; ++v) {
        int e = e0 + v * 256;
        if (e < NE) atomicAdd(&bh[dst[e] >> 8], 1);
    }
    __syncthreads();
    for (int i = threadIdx.x; i < BUCKETS; i += 256)
        if (bh[i]) atomicAdd(&bhist[i], bh[i]);
}

__global__ __launch_bounds__(512) void bscan_k(const int* __restrict__ bhist,
                                               int* __restrict__ bcur) {
    __shared__ int buf[512];
    int tid = threadIdx.x;
    int v = (tid < BUCKETS) ? bhist[tid] : 0;
    buf[tid] = v;
    __syncthreads();
    for (int off = 1; off < 512; off <<= 1) {
        int t = (tid >= off) ? buf[tid - off] : 0;
        __syncthreads();
        buf[tid] += t;
        __syncthreads();
    }
    if (tid < BUCKETS) bcur[tid] = buf[tid] - v;
}

__global__ __launch_bounds__(256) void reorder_k(const int* __restrict__ src,
                                                 const int* __restrict__ dst,
                                                 int* __restrict__ bcur,
                                                 unsigned long long* __restrict__ ebuf) {
    __shared__ int hist[BUCKETS];
    __shared__ int base[BUCKETS];
    int tid = threadIdx.x;
    for (int i = tid; i < BUCKETS; i += 256) hist[i] = 0;
    __syncthreads();
    int e0 = blockIdx.x * (256 * RVPT) + tid;
    unsigned long long pair[RVPT];
    int pr[RVPT];
#pragma unroll
    for (int v = 0; v < RVPT; ++v) {
        int e = e0 + v * 256;
        if (e < NE) {
            int s = src[e], d = dst[e];
            pair[v] = ((unsigned long long)(unsigned)d << 32) | (unsigned)s;
            int b = d >> 8;
            int r = atomicAdd(&hist[b], 1);   // local rank < 1024, fits 12 bits
            pr[v] = (b << 12) | r;
        } else pr[v] = -1;
    }
    __syncthreads();
    for (int i = tid; i < BUCKETS; i += 256)
        base[i] = hist[i] ? atomicAdd(&bcur[i], hist[i]) : 0;
    __syncthreads();
#pragma unroll
    for (int v = 0; v < RVPT; ++v) {
        if (pr[v] >= 0) {
            int b = pr[v] >> 12, r = pr[v] & 4095;
            ebuf[(size_t)base[b] + r] = pair[v];
        }
    }
}

// per-bucket CSR: 512 threads for latency hiding; barriers outside divergent regions
__global__ __launch_bounds__(512) void pcsr_k(const unsigned long long* __restrict__ ebuf,
                                              const int* __restrict__ bend,
                                              int* __restrict__ row_ptr,
                                              int* __restrict__ col) {
    __shared__ int hist[256];
    __shared__ int wsum[4];
    int b = blockIdx.x;
    int tid = threadIdx.x;
    int beg = b ? bend[b - 1] : 0;
    int end = bend[b];

    if (tid < 256) hist[tid] = 0;
    __syncthreads();
    for (int e = beg + tid; e < end; e += 512)
        atomicAdd(&hist[(int)(ebuf[e] >> 32) & 255], 1);
    __syncthreads();

    int v = 0, excl = 0;
    if (tid < 256) {
        v = hist[tid];
        int lane = tid & 63, wid = tid >> 6;
        int s = v;
#pragma unroll
        for (int off = 1; off < 64; off <<= 1) {
            int t = __shfl_up(s, off);
            if (lane >= off) s += t;
        }
        if (lane == 63) wsum[wid] = s;
        // wsum consumers are in the same 4 waves; barrier below covers all
        excl = s - v;   // partial: add prev-wave sums after barrier
    }
    __syncthreads();
    if (tid < 256) {
        int wid = tid >> 6;
        int prev = 0;
#pragma unroll
        for (int w = 0; w < 4; ++w) prev += (w < wid) ? wsum[w] : 0;
        excl += beg + prev;
        int node = b * 256 + tid;
        if (node < NN) row_ptr[node] = excl;
        if (node == NN - 1) row_ptr[NN] = excl + v;
    }
    __syncthreads();
    if (tid < 256) hist[tid] = excl;
    __syncthreads();
    for (int e = beg + tid; e < end; e += 512) {
        unsigned long long p = ebuf[e];
        int d = (int)(p >> 32);
        int pos = atomicAdd(&hist[d & 255], 1);
        col[pos] = (int)(p & 0xffffffffu);
    }
}

// ---------------- weight convert (all 3 layers, one launch) ----------------
__global__ __launch_bounds__(256) void wcvt_all_k(
    const float* __restrict__ Wl1, const float* __restrict__ Wr1,
    const float* __restrict__ Wl2, const float* __restrict__ Wr2,
    const float* __restrict__ Wl3, const float* __restrict__ Wr3,
    unsigned short* __restrict__ wt1, unsigned short* __restrict__ wt2,
    unsigned short* __restrict__ wt3) {
    int idx = blockIdx.x * 256 + threadIdx.x;
    if (idx < 4096) {                       // L1: [64][64], DIN=32 DOUT=64
        int j = idx >> 6, k = idx & 63;
        float v = (k < 32) ? Wl1[k * 64 + j] : Wr1[(k - 32) * 64 + j];
        wt1[idx] = f2bs(v);
    } else if (idx < 16384) {               // L2: [96][128], DIN=64 DOUT=96
        int t = idx - 4096;
        int j = t / 128, k = t - j * 128;
        float v = (k < 64) ? Wl2[k * 96 + j] : Wr2[(k - 64) * 96 + j];
        wt2[t] = f2bs(v);
    } else if (idx < 40960) {               // L3: [128][192], DIN=96 DOUT=128
        int t = idx - 16384;
        int j = t / 192, k = t - j * 192;
        float v = (k < 96) ? Wl3[k * 128 + j] : Wr3[(k - 96) * 128 + j];
        wt3[t] = f2bs(v);
    }
}

// ---------------- layer-0 aggregation ----------------
__global__ __launch_bounds__(256) void agg0_k(const int* __restrict__ rp, const int* __restrict__ col,
                                              const float* __restrict__ x, unsigned short* __restrict__ magg) {
    int node = blockIdx.x * 4 + (threadIdx.x >> 6);
    int lane = threadIdx.x & 63;
    int fl = lane & 3, es = lane >> 2;
    int beg = rp[node], end = rp[node + 1];
    float acc = 0.0f;
    for (int e = beg + es; e < end; e += 16) {
        unsigned off = (unsigned)(col[e] * 3);
        if (fl < 3) acc += x[off + fl];
    }
    acc += __shfl(acc, lane + 32);
    acc += __shfl(acc, lane + 16);
    acc += __shfl(acc, lane + 8);
    acc += __shfl(acc, lane + 4);
    if (lane < 3) {
        float inv = 1.0f / fmaxf((float)(end - beg), 1.0f);
        magg[(size_t)node * 3 + lane] = f2bs(acc * inv);
    }
}

// ---------------- generic aggregation: hb bf16 [N,DIN] -> magg bf16 [N,DIN] ----------------
template<int DIN, int FL, int EPW>
__global__ __launch_bounds__(256) void agg_k(const int* __restrict__ rp, const int* __restrict__ col,
                                             const unsigned short* __restrict__ hb,
                                             unsigned short* __restrict__ magg) {
    int node = blockIdx.x * 4 + (threadIdx.x >> 6);
    int lane = threadIdx.x & 63;
    int fl = lane % FL;
    int es = lane / FL;
    int beg = rp[node], end = rp[node + 1];

    float a[8];
#pragma unroll
    for (int i = 0; i < 8; ++i) a[i] = 0.0f;

    if (es < EPW) {
        int e = beg + es;
        for (; e + EPW < end; e += 2 * EPW) {
            unsigned o0 = (unsigned)(col[e]       * DIN);   // 32-bit mul (max 9.6M)
            unsigned o1 = (unsigned)(col[e + EPW] * DIN);
            uint4 v0 = *(const uint4*)(hb + o0 + fl * 8);
            uint4 v1 = *(const uint4*)(hb + o1 + fl * 8);
            const unsigned short* p0 = (const unsigned short*)&v0;
            const unsigned short* p1 = (const unsigned short*)&v1;
#pragma unroll
            for (int i = 0; i < 8; ++i) a[i] += bsf(p0[i]) + bsf(p1[i]);
        }
        if (e < end) {
            unsigned o0 = (unsigned)(col[e] * DIN);
            uint4 v0 = *(const uint4*)(hb + o0 + fl * 8);
            const unsigned short* p0 = (const unsigned short*)&v0;
#pragma unroll
            for (int i = 0; i < 8; ++i) a[i] += bsf(p0[i]);
        }
    }

    if constexpr (FL == 4) {        // EPW=16
#pragma unroll
        for (int i = 0; i < 8; ++i) {
            a[i] += __shfl(a[i], lane + 4);
            a[i] += __shfl(a[i], lane + 8);
            a[i] += __shfl(a[i], lane + 16);
            a[i] += __shfl(a[i], lane + 32);
        }
    } else if constexpr (FL == 8) { // EPW=8
#pragma unroll
        for (int i = 0; i < 8; ++i) {
            a[i] += __shfl(a[i], lane + 8);
            a[i] += __shfl(a[i], lane + 16);
            a[i] += __shfl(a[i], lane + 32);
        }
    } else {                        // FL==12, EPW=5
#pragma unroll
        for (int i = 0; i < 8; ++i) {
            float g4 = __shfl(a[i], lane + 48);
            a[i] += __shfl(a[i], lane + 12);
            a[i] += __shfl(a[i], lane + 24);
            a[i] += g4;
        }
    }

    if (lane < FL) {
        float inv = 1.0f / fmaxf((float)(end - beg), 1.0f);
        unsigned short o[8];
#pragma unroll
        for (int i = 0; i < 8; ++i) o[i] = f2bs(a[i] * inv);
        *(uint4*)(magg + (size_t)node * DIN + fl * 8) = *(const uint4*)o;
    }
}

// ---------------- scalar update (layer 0 only, K=6) ----------------
template<int DIN, int DOUT, int CT>
__global__ __launch_bounds__(256) void gemm_k(
    const unsigned short* __restrict__ magg, const float* __restrict__ hx,
    const float* __restrict__ Wl, const float* __restrict__ bl, const float* __restrict__ Wr,
    unsigned short* __restrict__ hout)
{
    __shared__ float sm[32][DIN + 1];
    __shared__ float sh[32][DIN + 1];

    int tx = threadIdx.x;
    int base = blockIdx.x * 32;

    for (int f = tx; f < 32 * 3; f += 256) {
        int n = f / 3, k = f - n * 3;
        sm[n][k] = bsf(magg[(size_t)(base + n) * 3 + k]);
        sh[n][k] = hx[(size_t)(base + n) * 3 + k];
    }
    __syncthreads();

    int ng = tx >> 5, cg = tx & 31;
    float acc[4][CT];
#pragma unroll
    for (int m = 0; m < 4; ++m)
#pragma unroll
        for (int c = 0; c < CT; ++c) acc[m][c] = bl[cg * CT + c];

#pragma unroll
    for (int k = 0; k < 3; ++k) {
        float wl[CT], wr[CT];
#pragma unroll
        for (int c = 0; c < CT; ++c) {
            wl[c] = Wl[(size_t)k * DOUT + cg * CT + c];
            wr[c] = Wr[(size_t)k * DOUT + cg * CT + c];
        }
#pragma unroll
        for (int m = 0; m < 4; ++m) {
            float mv = sm[ng * 4 + m][k];
            float hv = sh[ng * 4 + m][k];
#pragma unroll
            for (int c = 0; c < CT; ++c)
                acc[m][c] = fmaf(mv, wl[c], fmaf(hv, wr[c], acc[m][c]));
        }
    }

#pragma unroll
    for (int m = 0; m < 4; ++m)
#pragma unroll
        for (int c = 0; c < CT; ++c) {
            float v = fmaxf(acc[m][c], 0.0f);
            hout[(size_t)(base + ng * 4 + m) * DOUT + cg * CT + c] = f2bs(v);
        }
}

// ---------------- MFMA update: relu([magg|h] @ Wt^T + bl), optional fused final ----------------
template<int DIN, int DOUT, bool FINAL>
__global__ __launch_bounds__(256) void mgemm_k(
    const unsigned short* __restrict__ magg, const unsigned short* __restrict__ h,
    const unsigned short* __restrict__ Wt, const float* __restrict__ bl,
    const float* __restrict__ Wf, const float* __restrict__ bfi,
    unsigned short* __restrict__ hout, float* __restrict__ out)
{
    constexpr int K2  = 2 * DIN;
    constexpr int STR = K2 + 8;
    constexpr int NT  = DOUT / 16;
    constexpr int KS  = K2 / 32;
    __shared__ unsigned short lA[64 * STR];
    __shared__ unsigned short lB[DOUT * STR];

    int tx = threadIdx.x;
    int base = blockIdx.x * 64;

    constexpr int CPM = DIN / 8;
    for (int c = tx; c < 64 * CPM; c += 256) {
        int n = c / CPM, o = (c - n * CPM) * 8;
        int node = base + n;
        uint4 vm = make_uint4(0, 0, 0, 0), vh = vm;
        if (node < NN) {
            vm = *(const uint4*)(magg + (size_t)node * DIN + o);
            vh = *(const uint4*)(h    + (size_t)node * DIN + o);
        }
        *(uint4*)(lA + n * STR + o)       = vm;
        *(uint4*)(lA + n * STR + DIN + o) = vh;
    }
    constexpr int CPW = K2 / 8;
    for (int c = tx; c < DOUT * CPW; c += 256) {
        int j = c / CPW, o = (c - j * CPW) * 8;
        *(uint4*)(lB + j * STR + o) = *(const uint4*)(Wt + (size_t)j * K2 + o);
    }
    __syncthreads();

    int lane = tx & 63;
    int wm = tx >> 6;
    int r16 = lane & 15, kg = lane >> 4;

    f32x4 acc[NT];
#pragma unroll
    for (int t = 0; t < NT; ++t) acc[t] = (f32x4){0.0f, 0.0f, 0.0f, 0.0f};

#pragma unroll
    for (int kk = 0; kk < KS; ++kk) {
        bf16x8 a = *(const bf16x8*)(lA + (wm * 16 + r16) * STR + kk * 32 + kg * 8);
#pragma unroll
        for (int t = 0; t < NT; ++t) {
            bf16x8 b = *(const bf16x8*)(lB + (t * 16 + r16) * STR + kk * 32 + kg * 8);
            acc[t] = __builtin_amdgcn_mfma_f32_16x16x32_bf16(a, b, acc[t], 0, 0, 0);
        }
    }

    if (!FINAL) {
#pragma unroll
        for (int t = 0; t < NT; ++t)
#pragma unroll
            for (int r = 0; r < 4; ++r) {
                int node = base + wm * 16 + kg * 4 + r;
                int colj = t * 16 + r16;
                float v = fmaxf(acc[t][r] + bl[colj], 0.0f);
                if (node < NN) hout[(size_t)node * DOUT + colj] = f2bs(v);
            }
    } else {
        __syncthreads();
        float* s4 = (float*)lB;
#pragma unroll
        for (int t = 0; t < NT; ++t)
#pragma unroll
            for (int r = 0; r < 4; ++r) {
                int nl = wm * 16 + kg * 4 + r;
                int colj = t * 16 + r16;
                s4[nl * 129 + colj] = fmaxf(acc[t][r] + bl[colj], 0.0f);
            }
        __syncthreads();
        int nl = tx >> 2, c = tx & 3;
        int node = base + nl;
        if (node < NN) {
            float a = bfi[c];
#pragma unroll 8
            for (int k = 0; k < 128; ++k)
                a = fmaf(s4[nl * 129 + k], Wf[k * 4 + c], a);
            out[(size_t)node * 4 + c] = 1.0f / (1.0f + expf(-a));
        }
    }
}

extern "C" void kernel_launch(void* const* d_in, const int* in_sizes, int n_in,
                              void* d_out, int out_size, void* d_ws, size_t ws_size,
                              hipStream_t stream) {
    const float* x   = (const float*)d_in[0];
    const int*   ei  = (const int*)d_in[1];
    const int*   src = ei;
    const int*   dst = ei + NE;
    const float* Wl0 = (const float*)d_in[2];
    const float* bl0 = (const float*)d_in[3];
    const float* Wr0 = (const float*)d_in[4];
    const float* Wl1 = (const float*)d_in[5];
    const float* bl1 = (const float*)d_in[6];
    const float* Wr1 = (const float*)d_in[7];
    const float* Wl2 = (const float*)d_in[8];
    const float* bl2 = (const float*)d_in[9];
    const float* Wr2 = (const float*)d_in[10];
    const float* Wl3 = (const float*)d_in[11];
    const float* bl3 = (const float*)d_in[12];
    const float* Wr3 = (const float*)d_in[13];
    const float* Wf  = (const float*)d_in[14];
    const float* bf  = (const float*)d_in[15];
    float* out = (float*)d_out;

    // ws (ints): row_ptr[NN+2] | bhist[512] | bcur[512] | col[NE] | pad -> 64B-aligned bf16 region
    size_t ints = (size_t)(NN + 2) + 512 + 512 + NE;
    ints = (ints + 15) & ~(size_t)15;
    size_t need = ints * 4 + (size_t)NN * (96 + 32 + 64 + 96) * 2
                + (size_t)(64 * 64 + 96 * 128 + 128 * 192) * 2;
    if (ws_size < need) return;

    int* row_ptr = (int*)d_ws;
    int* bhist   = row_ptr + NN + 2;
    int* bcur    = bhist + 512;
    int* col     = bcur + 512;
    unsigned short* magg = (unsigned short*)((char*)d_ws + ints * 4);
    unsigned long long* ebuf = (unsigned long long*)magg;    // dead before magg is born
    unsigned short* h1   = magg + (size_t)NN * 96;
    unsigned short* h2   = h1 + (size_t)NN * 32;
    unsigned short* h3   = h2 + (size_t)NN * 64;
    unsigned short* wt1  = h3 + (size_t)NN * 96;
    unsigned short* wt2  = wt1 + 64 * 64;
    unsigned short* wt3  = wt2 + 96 * 128;

    // weight conversion (one launch)
    wcvt_all_k<<<160, 256, 0, stream>>>(Wl1, Wr1, Wl2, Wr2, Wl3, Wr3, wt1, wt2, wt3);

    // CSR build
    hipMemsetAsync(bhist, 0, 512 * sizeof(int), stream);
    const int EB = (NE + 256 * RVPT - 1) / (256 * RVPT);    // 1563
    bhist_k<<<EB, 256, 0, stream>>>(dst, bhist);
    bscan_k<<<1, 512, 0, stream>>>(bhist, bcur);
    reorder_k<<<EB, 256, 0, stream>>>(src, dst, bcur, ebuf);
    pcsr_k<<<BUCKETS, 512, 0, stream>>>(ebuf, bcur, row_ptr, col);

    const int AGRID = NN / 4;
    const int MG    = (NN + 63) / 64;

    // layer 0: x(3) -> h1(32)  (scalar, K=6)
    agg0_k<<<AGRID, 256, 0, stream>>>(row_ptr, col, x, magg);
    gemm_k<3, 32, 1><<<NN / 32, 256, 0, stream>>>(magg, x, Wl0, bl0, Wr0, h1);

    // layer 1: h1(32) -> h2(64)
    agg_k<32, 4, 16><<<AGRID, 256, 0, stream>>>(row_ptr, col, h1, magg);
    mgemm_k<32, 64, false><<<MG, 256, 0, stream>>>(
        magg, h1, wt1, bl1, nullptr, nullptr, h2, nullptr);

    // layer 2: h2(64) -> h3(96)
    agg_k<64, 8, 8><<<AGRID, 256, 0, stream>>>(row_ptr, col, h2, magg);
    mgemm_k<64, 96, false><<<MG, 256, 0, stream>>>(
        magg, h2, wt2, bl2, nullptr, nullptr, h3, nullptr);

    // layer 3 + final: h3(96) -> [128] -> out(4)
    agg_k<96, 12, 5><<<AGRID, 256, 0, stream>>>(row_ptr, col, h3, magg);
    mgemm_k<96, 128, true><<<MG, 256, 0, stream>>>(
        magg, h3, wt3, bl3, Wf, bf, nullptr, out);
}

// Round 11
// 294.798 us; speedup vs baseline: 1.2948x; 1.2948x over previous
//
#include <hip/hip_runtime.h>
#include <math.h>

#define NN 100000
#define NE 1600000
#define BUCKETS ((NN + 255) >> 8)              // 391 buckets of 256 nodes
#define RTH 1024                                // threads in reorder/bhist blocks
#define RVPT 4                                  // edges per thread (4096 edges/block)

typedef short bf16x8 __attribute__((ext_vector_type(8)));
typedef float f32x4 __attribute__((ext_vector_type(4)));

__device__ inline float bsf(unsigned short u) { return __uint_as_float(((unsigned)u) << 16); }
__device__ inline unsigned short f2bs(float f) {           // RNE, matches np/hw bf16
    unsigned u = __float_as_uint(f);
    return (unsigned short)((u + 0x7fffu + ((u >> 16) & 1u)) >> 16);
}

// ---------------- CSR build (no scattered global atomics) ----------------
// 4096 edges/block keeps ~10.5 edges per bucket-window (write density -> no amplification);
// 1024 threads = 16 waves/block hides the scattered-access latency.
__global__ __launch_bounds__(RTH) void bhist_k(const int* __restrict__ dst,
                                               int* __restrict__ bhist) {
    __shared__ int bh[BUCKETS];
    for (int i = threadIdx.x; i < BUCKETS; i += RTH) bh[i] = 0;
    __syncthreads();
    int e0 = blockIdx.x * (RTH * RVPT) + threadIdx.x;
#pragma unroll
    for (int v = 0; v < RVPT; ++v) {
        int e = e0 + v * RTH;
        if (e < NE) atomicAdd(&bh[dst[e] >> 8], 1);
    }
    __syncthreads();
    for (int i = threadIdx.x; i < BUCKETS; i += RTH)
        if (bh[i]) atomicAdd(&bhist[i], bh[i]);
}

__global__ __launch_bounds__(512) void bscan_k(const int* __restrict__ bhist,
                                               int* __restrict__ bcur) {
    __shared__ int buf[512];
    int tid = threadIdx.x;
    int v = (tid < BUCKETS) ? bhist[tid] : 0;
    buf[tid] = v;
    __syncthreads();
    for (int off = 1; off < 512; off <<= 1) {
        int t = (tid >= off) ? buf[tid - off] : 0;
        __syncthreads();
        buf[tid] += t;
        __syncthreads();
    }
    if (tid < BUCKETS) bcur[tid] = buf[tid] - v;
}

__global__ __launch_bounds__(RTH) void reorder_k(const int* __restrict__ src,
                                                 const int* __restrict__ dst,
                                                 int* __restrict__ bcur,
                                                 unsigned long long* __restrict__ ebuf) {
    __shared__ int hist[BUCKETS];
    __shared__ int base[BUCKETS];
    int tid = threadIdx.x;
    for (int i = tid; i < BUCKETS; i += RTH) hist[i] = 0;
    __syncthreads();
    int e0 = blockIdx.x * (RTH * RVPT) + tid;
    unsigned long long pair[RVPT];
    int pr[RVPT];
#pragma unroll
    for (int v = 0; v < RVPT; ++v) {
        int e = e0 + v * RTH;
        if (e < NE) {
            int s = src[e], d = dst[e];
            pair[v] = ((unsigned long long)(unsigned)d << 32) | (unsigned)s;
            int b = d >> 8;
            int r = atomicAdd(&hist[b], 1);   // local rank < 4096, fits 12 bits
            pr[v] = (b << 12) | r;
        } else pr[v] = -1;
    }
    __syncthreads();
    for (int i = tid; i < BUCKETS; i += RTH)
        base[i] = hist[i] ? atomicAdd(&bcur[i], hist[i]) : 0;
    __syncthreads();
#pragma unroll
    for (int v = 0; v < RVPT; ++v) {
        if (pr[v] >= 0) {
            int b = pr[v] >> 12, r = pr[v] & 4095;
            ebuf[(size_t)base[b] + r] = pair[v];
        }
    }
}

// per-bucket CSR: 512 threads; barriers outside divergent regions
__global__ __launch_bounds__(512) void pcsr_k(const unsigned long long* __restrict__ ebuf,
                                              const int* __restrict__ bend,
                                              int* __restrict__ row_ptr,
                                              int* __restrict__ col) {
    __shared__ int hist[256];
    __shared__ int wsum[4];
    int b = blockIdx.x;
    int tid = threadIdx.x;
    int beg = b ? bend[b - 1] : 0;
    int end = bend[b];

    if (tid < 256) hist[tid] = 0;
    __syncthreads();
    for (int e = beg + tid; e < end; e += 512)
        atomicAdd(&hist[(int)(ebuf[e] >> 32) & 255], 1);
    __syncthreads();

    int v = 0, excl = 0;
    if (tid < 256) {
        v = hist[tid];
        int lane = tid & 63, wid = tid >> 6;
        int s = v;
#pragma unroll
        for (int off = 1; off < 64; off <<= 1) {
            int t = __shfl_up(s, off);
            if (lane >= off) s += t;
        }
        if (lane == 63) wsum[wid] = s;
        excl = s - v;
    }
    __syncthreads();
    if (tid < 256) {
        int wid = tid >> 6;
        int prev = 0;
#pragma unroll
        for (int w = 0; w < 4; ++w) prev += (w < wid) ? wsum[w] : 0;
        excl += beg + prev;
        int node = b * 256 + tid;
        if (node < NN) row_ptr[node] = excl;
        if (node == NN - 1) row_ptr[NN] = excl + v;
    }
    __syncthreads();
    if (tid < 256) hist[tid] = excl;
    __syncthreads();
    for (int e = beg + tid; e < end; e += 512) {
        unsigned long long p = ebuf[e];
        int d = (int)(p >> 32);
        int pos = atomicAdd(&hist[d & 255], 1);
        col[pos] = (int)(p & 0xffffffffu);
    }
}

// ---------------- weight convert (all 3 layers, one launch) ----------------
__global__ __launch_bounds__(256) void wcvt_all_k(
    const float* __restrict__ Wl1, const float* __restrict__ Wr1,
    const float* __restrict__ Wl2, const float* __restrict__ Wr2,
    const float* __restrict__ Wl3, const float* __restrict__ Wr3,
    unsigned short* __restrict__ wt1, unsigned short* __restrict__ wt2,
    unsigned short* __restrict__ wt3) {
    int idx = blockIdx.x * 256 + threadIdx.x;
    if (idx < 4096) {                       // L1: [64][64]
        int j = idx >> 6, k = idx & 63;
        float v = (k < 32) ? Wl1[k * 64 + j] : Wr1[(k - 32) * 64 + j];
        wt1[idx] = f2bs(v);
    } else if (idx < 16384) {               // L2: [96][128]
        int t = idx - 4096;
        int j = t / 128, k = t - j * 128;
        float v = (k < 64) ? Wl2[k * 96 + j] : Wr2[(k - 64) * 96 + j];
        wt2[t] = f2bs(v);
    } else if (idx < 40960) {               // L3: [128][192]
        int t = idx - 16384;
        int j = t / 192, k = t - j * 192;
        float v = (k < 96) ? Wl3[k * 128 + j] : Wr3[(k - 96) * 128 + j];
        wt3[t] = f2bs(v);
    }
}

// ---------------- layer-0 aggregation ----------------
__global__ __launch_bounds__(256) void agg0_k(const int* __restrict__ rp, const int* __restrict__ col,
                                              const float* __restrict__ x, unsigned short* __restrict__ magg) {
    int node = blockIdx.x * 4 + (threadIdx.x >> 6);
    int lane = threadIdx.x & 63;
    int fl = lane & 3, es = lane >> 2;
    int beg = rp[node], end = rp[node + 1];
    float acc = 0.0f;
    for (int e = beg + es; e < end; e += 16) {
        unsigned off = (unsigned)(col[e] * 3);
        if (fl < 3) acc += x[off + fl];
    }
    acc += __shfl(acc, lane + 32);
    acc += __shfl(acc, lane + 16);
    acc += __shfl(acc, lane + 8);
    acc += __shfl(acc, lane + 4);
    if (lane < 3) {
        float inv = 1.0f / fmaxf((float)(end - beg), 1.0f);
        magg[(size_t)node * 3 + lane] = f2bs(acc * inv);
    }
}

// ---------------- generic aggregation: hb bf16 [N,DIN] -> magg bf16 [N,DIN] ----------------
template<int DIN, int FL, int EPW>
__global__ __launch_bounds__(256) void agg_k(const int* __restrict__ rp, const int* __restrict__ col,
                                             const unsigned short* __restrict__ hb,
                                             unsigned short* __restrict__ magg) {
    int node = blockIdx.x * 4 + (threadIdx.x >> 6);
    int lane = threadIdx.x & 63;
    int fl = lane % FL;
    int es = lane / FL;
    int beg = rp[node], end = rp[node + 1];

    float a[8];
#pragma unroll
    for (int i = 0; i < 8; ++i) a[i] = 0.0f;

    if (es < EPW) {
        int e = beg + es;
        for (; e + EPW < end; e += 2 * EPW) {
            unsigned o0 = (unsigned)(col[e]       * DIN);
            unsigned o1 = (unsigned)(col[e + EPW] * DIN);
            uint4 v0 = *(const uint4*)(hb + o0 + fl * 8);
            uint4 v1 = *(const uint4*)(hb + o1 + fl * 8);
            const unsigned short* p0 = (const unsigned short*)&v0;
            const unsigned short* p1 = (const unsigned short*)&v1;
#pragma unroll
            for (int i = 0; i < 8; ++i) a[i] += bsf(p0[i]) + bsf(p1[i]);
        }
        if (e < end) {
            unsigned o0 = (unsigned)(col[e] * DIN);
            uint4 v0 = *(const uint4*)(hb + o0 + fl * 8);
            const unsigned short* p0 = (const unsigned short*)&v0;
#pragma unroll
            for (int i = 0; i < 8; ++i) a[i] += bsf(p0[i]);
        }
    }

    if constexpr (FL == 4) {
#pragma unroll
        for (int i = 0; i < 8; ++i) {
            a[i] += __shfl(a[i], lane + 4);
            a[i] += __shfl(a[i], lane + 8);
            a[i] += __shfl(a[i], lane + 16);
            a[i] += __shfl(a[i], lane + 32);
        }
    } else if constexpr (FL == 8) {
#pragma unroll
        for (int i = 0; i < 8; ++i) {
            a[i] += __shfl(a[i], lane + 8);
            a[i] += __shfl(a[i], lane + 16);
            a[i] += __shfl(a[i], lane + 32);
        }
    } else {                        // FL==12, EPW=5
#pragma unroll
        for (int i = 0; i < 8; ++i) {
            float g4 = __shfl(a[i], lane + 48);
            a[i] += __shfl(a[i], lane + 12);
            a[i] += __shfl(a[i], lane + 24);
            a[i] += g4;
        }
    }

    if (lane < FL) {
        float inv = 1.0f / fmaxf((float)(end - beg), 1.0f);
        unsigned short o[8];
#pragma unroll
        for (int i = 0; i < 8; ++i) o[i] = f2bs(a[i] * inv);
        *(uint4*)(magg + (size_t)node * DIN + fl * 8) = *(const uint4*)o;
    }
}

// ---------------- scalar update (layer 0 only, K=6) ----------------
template<int DIN, int DOUT, int CT>
__global__ __launch_bounds__(256) void gemm_k(
    const unsigned short* __restrict__ magg, const float* __restrict__ hx,
    const float* __restrict__ Wl, const float* __restrict__ bl, const float* __restrict__ Wr,
    unsigned short* __restrict__ hout)
{
    __shared__ float sm[32][DIN + 1];
    __shared__ float sh[32][DIN + 1];

    int tx = threadIdx.x;
    int base = blockIdx.x * 32;

    for (int f = tx; f < 32 * 3; f += 256) {
        int n = f / 3, k = f - n * 3;
        sm[n][k] = bsf(magg[(size_t)(base + n) * 3 + k]);
        sh[n][k] = hx[(size_t)(base + n) * 3 + k];
    }
    __syncthreads();

    int ng = tx >> 5, cg = tx & 31;
    float acc[4][CT];
#pragma unroll
    for (int m = 0; m < 4; ++m)
#pragma unroll
        for (int c = 0; c < CT; ++c) acc[m][c] = bl[cg * CT + c];

#pragma unroll
    for (int k = 0; k < 3; ++k) {
        float wl[CT], wr[CT];
#pragma unroll
        for (int c = 0; c < CT; ++c) {
            wl[c] = Wl[(size_t)k * DOUT + cg * CT + c];
            wr[c] = Wr[(size_t)k * DOUT + cg * CT + c];
        }
#pragma unroll
        for (int m = 0; m < 4; ++m) {
            float mv = sm[ng * 4 + m][k];
            float hv = sh[ng * 4 + m][k];
#pragma unroll
            for (int c = 0; c < CT; ++c)
                acc[m][c] = fmaf(mv, wl[c], fmaf(hv, wr[c], acc[m][c]));
        }
    }

#pragma unroll
    for (int m = 0; m < 4; ++m)
#pragma unroll
        for (int c = 0; c < CT; ++c) {
            float v = fmaxf(acc[m][c], 0.0f);
            hout[(size_t)(base + ng * 4 + m) * DOUT + cg * CT + c] = f2bs(v);
        }
}

// ---------------- MFMA update: relu([magg|h] @ Wt^T + bl), optional fused final ----------------
template<int DIN, int DOUT, bool FINAL>
__global__ __launch_bounds__(256) void mgemm_k(
    const unsigned short* __restrict__ magg, const unsigned short* __restrict__ h,
    const unsigned short* __restrict__ Wt, const float* __restrict__ bl,
    const float* __restrict__ Wf, const float* __restrict__ bfi,
    unsigned short* __restrict__ hout, float* __restrict__ out)
{
    constexpr int K2  = 2 * DIN;
    constexpr int STR = K2 + 8;
    constexpr int NT  = DOUT / 16;
    constexpr int KS  = K2 / 32;
    __shared__ unsigned short lA[64 * STR];
    __shared__ unsigned short lB[DOUT * STR];

    int tx = threadIdx.x;
    int base = blockIdx.x * 64;

    constexpr int CPM = DIN / 8;
    for (int c = tx; c < 64 * CPM; c += 256) {
        int n = c / CPM, o = (c - n * CPM) * 8;
        int node = base + n;
        uint4 vm = make_uint4(0, 0, 0, 0), vh = vm;
        if (node < NN) {
            vm = *(const uint4*)(magg + (size_t)node * DIN + o);
            vh = *(const uint4*)(h    + (size_t)node * DIN + o);
        }
        *(uint4*)(lA + n * STR + o)       = vm;
        *(uint4*)(lA + n * STR + DIN + o) = vh;
    }
    constexpr int CPW = K2 / 8;
    for (int c = tx; c < DOUT * CPW; c += 256) {
        int j = c / CPW, o = (c - j * CPW) * 8;
        *(uint4*)(lB + j * STR + o) = *(const uint4*)(Wt + (size_t)j * K2 + o);
    }
    __syncthreads();

    int lane = tx & 63;
    int wm = tx >> 6;
    int r16 = lane & 15, kg = lane >> 4;

    f32x4 acc[NT];
#pragma unroll
    for (int t = 0; t < NT; ++t) acc[t] = (f32x4){0.0f, 0.0f, 0.0f, 0.0f};

#pragma unroll
    for (int kk = 0; kk < KS; ++kk) {
        bf16x8 a = *(const bf16x8*)(lA + (wm * 16 + r16) * STR + kk * 32 + kg * 8);
#pragma unroll
        for (int t = 0; t < NT; ++t) {
            bf16x8 b = *(const bf16x8*)(lB + (t * 16 + r16) * STR + kk * 32 + kg * 8);
            acc[t] = __builtin_amdgcn_mfma_f32_16x16x32_bf16(a, b, acc[t], 0, 0, 0);
        }
    }

    if (!FINAL) {
#pragma unroll
        for (int t = 0; t < NT; ++t)
#pragma unroll
            for (int r = 0; r < 4; ++r) {
                int node = base + wm * 16 + kg * 4 + r;
                int colj = t * 16 + r16;
                float v = fmaxf(acc[t][r] + bl[colj], 0.0f);
                if (node < NN) hout[(size_t)node * DOUT + colj] = f2bs(v);
            }
    } else {
        __syncthreads();
        float* s4 = (float*)lB;
#pragma unroll
        for (int t = 0; t < NT; ++t)
#pragma unroll
            for (int r = 0; r < 4; ++r) {
                int nl = wm * 16 + kg * 4 + r;
                int colj = t * 16 + r16;
                s4[nl * 129 + colj] = fmaxf(acc[t][r] + bl[colj], 0.0f);
            }
        __syncthreads();
        int nl = tx >> 2, c = tx & 3;
        int node = base + nl;
        if (node < NN) {
            float a = bfi[c];
#pragma unroll 8
            for (int k = 0; k < 128; ++k)
                a = fmaf(s4[nl * 129 + k], Wf[k * 4 + c], a);
            out[(size_t)node * 4 + c] = 1.0f / (1.0f + expf(-a));
        }
    }
}

extern "C" void kernel_launch(void* const* d_in, const int* in_sizes, int n_in,
                              void* d_out, int out_size, void* d_ws, size_t ws_size,
                              hipStream_t stream) {
    const float* x   = (const float*)d_in[0];
    const int*   ei  = (const int*)d_in[1];
    const int*   src = ei;
    const int*   dst = ei + NE;
    const float* Wl0 = (const float*)d_in[2];
    const float* bl0 = (const float*)d_in[3];
    const float* Wr0 = (const float*)d_in[4];
    const float* Wl1 = (const float*)d_in[5];
    const float* bl1 = (const float*)d_in[6];
    const float* Wr1 = (const float*)d_in[7];
    const float* Wl2 = (const float*)d_in[8];
    const float* bl2 = (const float*)d_in[9];
    const float* Wr2 = (const float*)d_in[10];
    const float* Wl3 = (const float*)d_in[11];
    const float* bl3 = (const float*)d_in[12];
    const float* Wr3 = (const float*)d_in[13];
    const float* Wf  = (const float*)d_in[14];
    const float* bf  = (const float*)d_in[15];
    float* out = (float*)d_out;

    // ws (ints): row_ptr[NN+2] | bhist[512] | bcur[512] | col[NE] | pad -> 64B-aligned bf16 region
    size_t ints = (size_t)(NN + 2) + 512 + 512 + NE;
    ints = (ints + 15) & ~(size_t)15;
    size_t need = ints * 4 + (size_t)NN * (96 + 32 + 64 + 96) * 2
                + (size_t)(64 * 64 + 96 * 128 + 128 * 192) * 2;
    if (ws_size < need) return;

    int* row_ptr = (int*)d_ws;
    int* bhist   = row_ptr + NN + 2;
    int* bcur    = bhist + 512;
    int* col     = bcur + 512;
    unsigned short* magg = (unsigned short*)((char*)d_ws + ints * 4);
    unsigned long long* ebuf = (unsigned long long*)magg;    // dead before magg is born
    unsigned short* h1   = magg + (size_t)NN * 96;
    unsigned short* h2   = h1 + (size_t)NN * 32;
    unsigned short* h3   = h2 + (size_t)NN * 64;
    unsigned short* wt1  = h3 + (size_t)NN * 96;
    unsigned short* wt2  = wt1 + 64 * 64;
    unsigned short* wt3  = wt2 + 96 * 128;

    // weight conversion (one launch)
    wcvt_all_k<<<160, 256, 0, stream>>>(Wl1, Wr1, Wl2, Wr2, Wl3, Wr3, wt1, wt2, wt3);

    // CSR build: 4096 edges/block (write density) x 16 waves (latency hiding)
    hipMemsetAsync(bhist, 0, 512 * sizeof(int), stream);
    const int EB = (NE + RTH * RVPT - 1) / (RTH * RVPT);    // 391
    bhist_k<<<EB, RTH, 0, stream>>>(dst, bhist);
    bscan_k<<<1, 512, 0, stream>>>(bhist, bcur);
    reorder_k<<<EB, RTH, 0, stream>>>(src, dst, bcur, ebuf);
    pcsr_k<<<BUCKETS, 512, 0, stream>>>(ebuf, bcur, row_ptr, col);

    const int AGRID = NN / 4;
    const int MG    = (NN + 63) / 64;

    // layer 0: x(3) -> h1(32)  (scalar, K=6)
    agg0_k<<<AGRID, 256, 0, stream>>>(row_ptr, col, x, magg);
    gemm_k<3, 32, 1><<<NN / 32, 256, 0, stream>>>(magg, x, Wl0, bl0, Wr0, h1);

    // layer 1: h1(32) -> h2(64)
    agg_k<32, 4, 16><<<AGRID, 256, 0, stream>>>(row_ptr, col, h1, magg);
    mgemm_k<32, 64, false><<<MG, 256, 0, stream>>>(
        magg, h1, wt1, bl1, nullptr, nullptr, h2, nullptr);

    // layer 2: h2(64) -> h3(96)
    agg_k<64, 8, 8><<<AGRID, 256, 0, stream>>>(row_ptr, col, h2, magg);
    mgemm_k<64, 96, false><<<MG, 256, 0, stream>>>(
        magg, h2, wt2, bl2, nullptr, nullptr, h3, nullptr);

    // layer 3 + final: h3(96) -> [128] -> out(4)
    agg_k<96, 12, 5><<<AGRID, 256, 0, stream>>>(row_ptr, col, h3, magg);
    mgemm_k<96, 128, true><<<MG, 256, 0, stream>>>(
        magg, h3, wt3, bl3, Wf, bf, nullptr, out);
}

// Round 12
// 289.141 us; speedup vs baseline: 1.3201x; 1.0196x over previous
//
#include <hip/hip_runtime.h>
#include <math.h>

#define NN 100000
#define NE 1600000
#define BUCKETS ((NN + 255) >> 8)              // 391 buckets of 256 nodes
#define RTH 1024                                // threads in reorder/bhist blocks
#define RVPT 4                                  // edges per thread (4096 edges/block)

typedef short bf16x8 __attribute__((ext_vector_type(8)));
typedef float f32x4 __attribute__((ext_vector_type(4)));

__device__ inline float bsf(unsigned short u) { return __uint_as_float(((unsigned)u) << 16); }
__device__ inline unsigned short f2bs(float f) {           // RNE, matches np/hw bf16
    unsigned u = __float_as_uint(f);
    return (unsigned short)((u + 0x7fffu + ((u >> 16) & 1u)) >> 16);
}

// ---------------- CSR build (no scattered global atomics) ----------------
__global__ __launch_bounds__(RTH) void bhist_k(const int* __restrict__ dst,
                                               int* __restrict__ bhist) {
    __shared__ int bh[BUCKETS];
    for (int i = threadIdx.x; i < BUCKETS; i += RTH) bh[i] = 0;
    __syncthreads();
    int e0 = blockIdx.x * (RTH * RVPT) + threadIdx.x;
#pragma unroll
    for (int v = 0; v < RVPT; ++v) {
        int e = e0 + v * RTH;
        if (e < NE) atomicAdd(&bh[dst[e] >> 8], 1);
    }
    __syncthreads();
    for (int i = threadIdx.x; i < BUCKETS; i += RTH)
        if (bh[i]) atomicAdd(&bhist[i], bh[i]);
}

__global__ __launch_bounds__(512) void bscan_k(const int* __restrict__ bhist,
                                               int* __restrict__ bcur) {
    __shared__ int buf[512];
    int tid = threadIdx.x;
    int v = (tid < BUCKETS) ? bhist[tid] : 0;
    buf[tid] = v;
    __syncthreads();
    for (int off = 1; off < 512; off <<= 1) {
        int t = (tid >= off) ? buf[tid - off] : 0;
        __syncthreads();
        buf[tid] += t;
        __syncthreads();
    }
    if (tid < BUCKETS) bcur[tid] = buf[tid] - v;
}

__global__ __launch_bounds__(RTH) void reorder_k(const int* __restrict__ src,
                                                 const int* __restrict__ dst,
                                                 int* __restrict__ bcur,
                                                 unsigned long long* __restrict__ ebuf) {
    __shared__ int hist[BUCKETS];
    __shared__ int base[BUCKETS];
    int tid = threadIdx.x;
    for (int i = tid; i < BUCKETS; i += RTH) hist[i] = 0;
    __syncthreads();
    int e0 = blockIdx.x * (RTH * RVPT) + tid;
    unsigned long long pair[RVPT];
    int pr[RVPT];
#pragma unroll
    for (int v = 0; v < RVPT; ++v) {
        int e = e0 + v * RTH;
        if (e < NE) {
            int s = src[e], d = dst[e];
            pair[v] = ((unsigned long long)(unsigned)d << 32) | (unsigned)s;
            int b = d >> 8;
            int r = atomicAdd(&hist[b], 1);   // local rank < 4096, fits 12 bits
            pr[v] = (b << 12) | r;
        } else pr[v] = -1;
    }
    __syncthreads();
    for (int i = tid; i < BUCKETS; i += RTH)
        base[i] = hist[i] ? atomicAdd(&bcur[i], hist[i]) : 0;
    __syncthreads();
#pragma unroll
    for (int v = 0; v < RVPT; ++v) {
        if (pr[v] >= 0) {
            int b = pr[v] >> 12, r = pr[v] & 4095;
            ebuf[(size_t)base[b] + r] = pair[v];
        }
    }
}

// per-bucket CSR: 512 threads; barriers outside divergent regions
__global__ __launch_bounds__(512) void pcsr_k(const unsigned long long* __restrict__ ebuf,
                                              const int* __restrict__ bend,
                                              int* __restrict__ row_ptr,
                                              int* __restrict__ col) {
    __shared__ int hist[256];
    __shared__ int wsum[4];
    int b = blockIdx.x;
    int tid = threadIdx.x;
    int beg = b ? bend[b - 1] : 0;
    int end = bend[b];

    if (tid < 256) hist[tid] = 0;
    __syncthreads();
    for (int e = beg + tid; e < end; e += 512)
        atomicAdd(&hist[(int)(ebuf[e] >> 32) & 255], 1);
    __syncthreads();

    int v = 0, excl = 0;
    if (tid < 256) {
        v = hist[tid];
        int lane = tid & 63, wid = tid >> 6;
        int s = v;
#pragma unroll
        for (int off = 1; off < 64; off <<= 1) {
            int t = __shfl_up(s, off);
            if (lane >= off) s += t;
        }
        if (lane == 63) wsum[wid] = s;
        excl = s - v;
    }
    __syncthreads();
    if (tid < 256) {
        int wid = tid >> 6;
        int prev = 0;
#pragma unroll
        for (int w = 0; w < 4; ++w) prev += (w < wid) ? wsum[w] : 0;
        excl += beg + prev;
        int node = b * 256 + tid;
        if (node < NN) row_ptr[node] = excl;
        if (node == NN - 1) row_ptr[NN] = excl + v;
    }
    __syncthreads();
    if (tid < 256) hist[tid] = excl;
    __syncthreads();
    for (int e = beg + tid; e < end; e += 512) {
        unsigned long long p = ebuf[e];
        int d = (int)(p >> 32);
        int pos = atomicAdd(&hist[d & 255], 1);
        col[pos] = (int)(p & 0xffffffffu);
    }
}

// ---------------- weight convert (all 3 layers, one launch) ----------------
__global__ __launch_bounds__(256) void wcvt_all_k(
    const float* __restrict__ Wl1, const float* __restrict__ Wr1,
    const float* __restrict__ Wl2, const float* __restrict__ Wr2,
    const float* __restrict__ Wl3, const float* __restrict__ Wr3,
    unsigned short* __restrict__ wt1, unsigned short* __restrict__ wt2,
    unsigned short* __restrict__ wt3) {
    int idx = blockIdx.x * 256 + threadIdx.x;
    if (idx < 4096) {                       // L1: [64][64]
        int j = idx >> 6, k = idx & 63;
        float v = (k < 32) ? Wl1[k * 64 + j] : Wr1[(k - 32) * 64 + j];
        wt1[idx] = f2bs(v);
    } else if (idx < 16384) {               // L2: [96][128]
        int t = idx - 4096;
        int j = t / 128, k = t - j * 128;
        float v = (k < 64) ? Wl2[k * 96 + j] : Wr2[(k - 64) * 96 + j];
        wt2[t] = f2bs(v);
    } else if (idx < 40960) {               // L3: [128][192]
        int t = idx - 16384;
        int j = t / 192, k = t - j * 192;
        float v = (k < 96) ? Wl3[k * 128 + j] : Wr3[(k - 96) * 128 + j];
        wt3[t] = f2bs(v);
    }
}

// ---------------- layer-0 aggregation ----------------
__global__ __launch_bounds__(256) void agg0_k(const int* __restrict__ rp, const int* __restrict__ col,
                                              const float* __restrict__ x, unsigned short* __restrict__ magg) {
    int node = blockIdx.x * 4 + (threadIdx.x >> 6);
    int lane = threadIdx.x & 63;
    int fl = lane & 3, es = lane >> 2;
    int beg = rp[node], end = rp[node + 1];
    float acc = 0.0f;
    for (int e = beg + es; e < end; e += 16) {
        unsigned off = (unsigned)(col[e] * 3);
        if (fl < 3) acc += x[off + fl];
    }
    acc += __shfl(acc, lane + 32);
    acc += __shfl(acc, lane + 16);
    acc += __shfl(acc, lane + 8);
    acc += __shfl(acc, lane + 4);
    if (lane < 3) {
        float inv = 1.0f / fmaxf((float)(end - beg), 1.0f);
        magg[(size_t)node * 3 + lane] = f2bs(acc * inv);
    }
}

// ---------------- generic aggregation: hb bf16 [N,DIN] -> magg bf16 [N,DIN] ----------------
// wave per node; FL lanes x 16B cover a row; EPW edge slots.
// 4-deep guaranteed load pipeline: always issue 4 row loads per slot iteration,
// clamping out-of-range edges to the e-row (L1-hot dup) and masking via fmaf(,0,).
template<int DIN, int FL, int EPW>
__global__ __launch_bounds__(256) void agg_k(const int* __restrict__ rp, const int* __restrict__ col,
                                             const unsigned short* __restrict__ hb,
                                             unsigned short* __restrict__ magg) {
    int node = blockIdx.x * 4 + (threadIdx.x >> 6);
    int lane = threadIdx.x & 63;
    int fl = lane % FL;
    int es = lane / FL;
    int beg = rp[node], end = rp[node + 1];

    float a[8];
#pragma unroll
    for (int i = 0; i < 8; ++i) a[i] = 0.0f;

    if (es < EPW) {
        for (int e = beg + es; e < end; e += 4 * EPW) {
            int e1 = e + EPW, e2 = e + 2 * EPW, e3 = e + 3 * EPW;
            bool b1 = e1 < end, b2 = e2 < end, b3 = e3 < end;
            unsigned o0 = (unsigned)(col[e] * DIN);
            unsigned o1 = (unsigned)(col[b1 ? e1 : e] * DIN);
            unsigned o2 = (unsigned)(col[b2 ? e2 : e] * DIN);
            unsigned o3 = (unsigned)(col[b3 ? e3 : e] * DIN);
            uint4 v0 = *(const uint4*)(hb + o0 + fl * 8);
            uint4 v1 = *(const uint4*)(hb + o1 + fl * 8);
            uint4 v2 = *(const uint4*)(hb + o2 + fl * 8);
            uint4 v3 = *(const uint4*)(hb + o3 + fl * 8);
            float m1 = b1 ? 1.0f : 0.0f;
            float m2 = b2 ? 1.0f : 0.0f;
            float m3 = b3 ? 1.0f : 0.0f;
            const unsigned short* p0 = (const unsigned short*)&v0;
            const unsigned short* p1 = (const unsigned short*)&v1;
            const unsigned short* p2 = (const unsigned short*)&v2;
            const unsigned short* p3 = (const unsigned short*)&v3;
#pragma unroll
            for (int i = 0; i < 8; ++i) {
                a[i] += bsf(p0[i]);
                a[i] = fmaf(bsf(p1[i]), m1, a[i]);
                a[i] = fmaf(bsf(p2[i]), m2, a[i]);
                a[i] = fmaf(bsf(p3[i]), m3, a[i]);
            }
        }
    }

    if constexpr (FL == 4) {        // EPW=16
#pragma unroll
        for (int i = 0; i < 8; ++i) {
            a[i] += __shfl(a[i], lane + 4);
            a[i] += __shfl(a[i], lane + 8);
            a[i] += __shfl(a[i], lane + 16);
            a[i] += __shfl(a[i], lane + 32);
        }
    } else if constexpr (FL == 8) { // EPW=8
#pragma unroll
        for (int i = 0; i < 8; ++i) {
            a[i] += __shfl(a[i], lane + 8);
            a[i] += __shfl(a[i], lane + 16);
            a[i] += __shfl(a[i], lane + 32);
        }
    } else {                        // FL==12, EPW=5
#pragma unroll
        for (int i = 0; i < 8; ++i) {
            float g4 = __shfl(a[i], lane + 48);
            a[i] += __shfl(a[i], lane + 12);
            a[i] += __shfl(a[i], lane + 24);
            a[i] += g4;
        }
    }

    if (lane < FL) {
        float inv = 1.0f / fmaxf((float)(end - beg), 1.0f);
        unsigned short o[8];
#pragma unroll
        for (int i = 0; i < 8; ++i) o[i] = f2bs(a[i] * inv);
        *(uint4*)(magg + (size_t)node * DIN + fl * 8) = *(const uint4*)o;
    }
}

// ---------------- scalar update (layer 0 only, K=6) ----------------
template<int DIN, int DOUT, int CT>
__global__ __launch_bounds__(256) void gemm_k(
    const unsigned short* __restrict__ magg, const float* __restrict__ hx,
    const float* __restrict__ Wl, const float* __restrict__ bl, const float* __restrict__ Wr,
    unsigned short* __restrict__ hout)
{
    __shared__ float sm[32][DIN + 1];
    __shared__ float sh[32][DIN + 1];

    int tx = threadIdx.x;
    int base = blockIdx.x * 32;

    for (int f = tx; f < 32 * 3; f += 256) {
        int n = f / 3, k = f - n * 3;
        sm[n][k] = bsf(magg[(size_t)(base + n) * 3 + k]);
        sh[n][k] = hx[(size_t)(base + n) * 3 + k];
    }
    __syncthreads();

    int ng = tx >> 5, cg = tx & 31;
    float acc[4][CT];
#pragma unroll
    for (int m = 0; m < 4; ++m)
#pragma unroll
        for (int c = 0; c < CT; ++c) acc[m][c] = bl[cg * CT + c];

#pragma unroll
    for (int k = 0; k < 3; ++k) {
        float wl[CT], wr[CT];
#pragma unroll
        for (int c = 0; c < CT; ++c) {
            wl[c] = Wl[(size_t)k * DOUT + cg * CT + c];
            wr[c] = Wr[(size_t)k * DOUT + cg * CT + c];
        }
#pragma unroll
        for (int m = 0; m < 4; ++m) {
            float mv = sm[ng * 4 + m][k];
            float hv = sh[ng * 4 + m][k];
#pragma unroll
            for (int c = 0; c < CT; ++c)
                acc[m][c] = fmaf(mv, wl[c], fmaf(hv, wr[c], acc[m][c]));
        }
    }

#pragma unroll
    for (int m = 0; m < 4; ++m)
#pragma unroll
        for (int c = 0; c < CT; ++c) {
            float v = fmaxf(acc[m][c], 0.0f);
            hout[(size_t)(base + ng * 4 + m) * DOUT + cg * CT + c] = f2bs(v);
        }
}

// ---------------- MFMA update: relu([magg|h] @ Wt^T + bl), optional fused final ----------------
template<int DIN, int DOUT, bool FINAL>
__global__ __launch_bounds__(256) void mgemm_k(
    const unsigned short* __restrict__ magg, const unsigned short* __restrict__ h,
    const unsigned short* __restrict__ Wt, const float* __restrict__ bl,
    const float* __restrict__ Wf, const float* __restrict__ bfi,
    unsigned short* __restrict__ hout, float* __restrict__ out)
{
    constexpr int K2  = 2 * DIN;
    constexpr int STR = K2 + 8;
    constexpr int NT  = DOUT / 16;
    constexpr int KS  = K2 / 32;
    __shared__ unsigned short lA[64 * STR];
    __shared__ unsigned short lB[DOUT * STR];

    int tx = threadIdx.x;
    int base = blockIdx.x * 64;

    constexpr int CPM = DIN / 8;
    for (int c = tx; c < 64 * CPM; c += 256) {
        int n = c / CPM, o = (c - n * CPM) * 8;
        int node = base + n;
        uint4 vm = make_uint4(0, 0, 0, 0), vh = vm;
        if (node < NN) {
            vm = *(const uint4*)(magg + (size_t)node * DIN + o);
            vh = *(const uint4*)(h    + (size_t)node * DIN + o);
        }
        *(uint4*)(lA + n * STR + o)       = vm;
        *(uint4*)(lA + n * STR + DIN + o) = vh;
    }
    constexpr int CPW = K2 / 8;
    for (int c = tx; c < DOUT * CPW; c += 256) {
        int j = c / CPW, o = (c - j * CPW) * 8;
        *(uint4*)(lB + j * STR + o) = *(const uint4*)(Wt + (size_t)j * K2 + o);
    }
    __syncthreads();

    int lane = tx & 63;
    int wm = tx >> 6;
    int r16 = lane & 15, kg = lane >> 4;

    f32x4 acc[NT];
#pragma unroll
    for (int t = 0; t < NT; ++t) acc[t] = (f32x4){0.0f, 0.0f, 0.0f, 0.0f};

#pragma unroll
    for (int kk = 0; kk < KS; ++kk) {
        bf16x8 a = *(const bf16x8*)(lA + (wm * 16 + r16) * STR + kk * 32 + kg * 8);
#pragma unroll
        for (int t = 0; t < NT; ++t) {
            bf16x8 b = *(const bf16x8*)(lB + (t * 16 + r16) * STR + kk * 32 + kg * 8);
            acc[t] = __builtin_amdgcn_mfma_f32_16x16x32_bf16(a, b, acc[t], 0, 0, 0);
        }
    }

    if (!FINAL) {
#pragma unroll
        for (int t = 0; t < NT; ++t)
#pragma unroll
            for (int r = 0; r < 4; ++r) {
                int node = base + wm * 16 + kg * 4 + r;
                int colj = t * 16 + r16;
                float v = fmaxf(acc[t][r] + bl[colj], 0.0f);
                if (node < NN) hout[(size_t)node * DOUT + colj] = f2bs(v);
            }
    } else {
        __syncthreads();
        float* s4 = (float*)lB;
#pragma unroll
        for (int t = 0; t < NT; ++t)
#pragma unroll
            for (int r = 0; r < 4; ++r) {
                int nl = wm * 16 + kg * 4 + r;
                int colj = t * 16 + r16;
                s4[nl * 129 + colj] = fmaxf(acc[t][r] + bl[colj], 0.0f);
            }
        __syncthreads();
        int nl = tx >> 2, c = tx & 3;
        int node = base + nl;
        if (node < NN) {
            float a = bfi[c];
#pragma unroll 8
            for (int k = 0; k < 128; ++k)
                a = fmaf(s4[nl * 129 + k], Wf[k * 4 + c], a);
            out[(size_t)node * 4 + c] = 1.0f / (1.0f + expf(-a));
        }
    }
}

extern "C" void kernel_launch(void* const* d_in, const int* in_sizes, int n_in,
                              void* d_out, int out_size, void* d_ws, size_t ws_size,
                              hipStream_t stream) {
    const float* x   = (const float*)d_in[0];
    const int*   ei  = (const int*)d_in[1];
    const int*   src = ei;
    const int*   dst = ei + NE;
    const float* Wl0 = (const float*)d_in[2];
    const float* bl0 = (const float*)d_in[3];
    const float* Wr0 = (const float*)d_in[4];
    const float* Wl1 = (const float*)d_in[5];
    const float* bl1 = (const float*)d_in[6];
    const float* Wr1 = (const float*)d_in[7];
    const float* Wl2 = (const float*)d_in[8];
    const float* bl2 = (const float*)d_in[9];
    const float* Wr2 = (const float*)d_in[10];
    const float* Wl3 = (const float*)d_in[11];
    const float* bl3 = (const float*)d_in[12];
    const float* Wr3 = (const float*)d_in[13];
    const float* Wf  = (const float*)d_in[14];
    const float* bf  = (const float*)d_in[15];
    float* out = (float*)d_out;

    // ws (ints): row_ptr[NN+2] | bhist[512] | bcur[512] | col[NE] | pad -> 64B-aligned bf16 region
    size_t ints = (size_t)(NN + 2) + 512 + 512 + NE;
    ints = (ints + 15) & ~(size_t)15;
    size_t need = ints * 4 + (size_t)NN * (96 + 32 + 64 + 96) * 2
                + (size_t)(64 * 64 + 96 * 128 + 128 * 192) * 2;
    if (ws_size < need) return;

    int* row_ptr = (int*)d_ws;
    int* bhist   = row_ptr + NN + 2;
    int* bcur    = bhist + 512;
    int* col     = bcur + 512;
    unsigned short* magg = (unsigned short*)((char*)d_ws + ints * 4);
    unsigned long long* ebuf = (unsigned long long*)magg;    // dead before magg is born
    unsigned short* h1   = magg + (size_t)NN * 96;
    unsigned short* h2   = h1 + (size_t)NN * 32;
    unsigned short* h3   = h2 + (size_t)NN * 64;
    unsigned short* wt1  = h3 + (size_t)NN * 96;
    unsigned short* wt2  = wt1 + 64 * 64;
    unsigned short* wt3  = wt2 + 96 * 128;

    // weight conversion (one launch)
    wcvt_all_k<<<160, 256, 0, stream>>>(Wl1, Wr1, Wl2, Wr2, Wl3, Wr3, wt1, wt2, wt3);

    // CSR build
    hipMemsetAsync(bhist, 0, 512 * sizeof(int), stream);
    const int EB = (NE + RTH * RVPT - 1) / (RTH * RVPT);    // 391
    bhist_k<<<EB, RTH, 0, stream>>>(dst, bhist);
    bscan_k<<<1, 512, 0, stream>>>(bhist, bcur);
    reorder_k<<<EB, RTH, 0, stream>>>(src, dst, bcur, ebuf);
    pcsr_k<<<BUCKETS, 512, 0, stream>>>(ebuf, bcur, row_ptr, col);

    const int AGRID = NN / 4;
    const int MG    = (NN + 63) / 64;

    // layer 0: x(3) -> h1(32)  (scalar, K=6)
    agg0_k<<<AGRID, 256, 0, stream>>>(row_ptr, col, x, magg);
    gemm_k<3, 32, 1><<<NN / 32, 256, 0, stream>>>(magg, x, Wl0, bl0, Wr0, h1);

    // layer 1: h1(32) -> h2(64)
    agg_k<32, 4, 16><<<AGRID, 256, 0, stream>>>(row_ptr, col, h1, magg);
    mgemm_k<32, 64, false><<<MG, 256, 0, stream>>>(
        magg, h1, wt1, bl1, nullptr, nullptr, h2, nullptr);

    // layer 2: h2(64) -> h3(96)
    agg_k<64, 8, 8><<<AGRID, 256, 0, stream>>>(row_ptr, col, h2, magg);
    mgemm_k<64, 96, false><<<MG, 256, 0, stream>>>(
        magg, h2, wt2, bl2, nullptr, nullptr, h3, nullptr);

    // layer 3 + final: h3(96) -> [128] -> out(4)
    agg_k<96, 12, 5><<<AGRID, 256, 0, stream>>>(row_ptr, col, h3, magg);
    mgemm_k<96, 128, true><<<MG, 256, 0, stream>>>(
        magg, h3, wt3, bl3, Wf, bf, nullptr, out);
}